// Round 5
// baseline (950.014 us; speedup 1.0000x reference)
//
#include <hip/hip_runtime.h>
#include <hip/hip_bf16.h>

typedef unsigned short u16;
typedef __bf16 bf16x8 __attribute__((ext_vector_type(8)));
typedef float f32x4 __attribute__((ext_vector_type(4)));
typedef float f32x16 __attribute__((ext_vector_type(16)));

#define NROWS 32768
#define H 512
#define NS 8
#define NR 64
#define NT 12

// workspace layout (bytes)
#define WS_W1T   0            // [8][512 n][512 k] bf16 = 4194304
#define WS_UCT   4194304      // [512 r][512 k] bf16    = 524288
#define WS_W2T   4718592      // [8][16 t][512 k] bf16  = 131072
#define WS_CVEC  4849664      // [8][64] f32            = 2048
#define WS_ALPH  4851712      // [8][32768] f32         = 1048576

union BFU { __bf16 h; u16 u; };
__device__ __forceinline__ u16 f2bf(float v) { BFU b; b.h = (__bf16)v; return b.u; }

__device__ __forceinline__ void gload16(const u16* g, u16* l) {
  __builtin_amdgcn_global_load_lds(
      (const __attribute__((address_space(1))) unsigned int*)g,
      (__attribute__((address_space(3))) unsigned int*)l, 16, 0, 0);
}

// ---------- prep: batched transpose + cast to bf16 ----------
__global__ __launch_bounds__(256) void transpose_cast(const float* __restrict__ in,
    u16* __restrict__ out, int Rr, int Cc, int Cpad) {
  __shared__ float tile[32][33];
  int b = blockIdx.z, r0 = blockIdx.x * 32, c0 = blockIdx.y * 32;
  int tx = threadIdx.x, ty = threadIdx.y;
#pragma unroll
  for (int i = 0; i < 4; i++) {
    int r = r0 + ty + i * 8, c = c0 + tx;
    float v = 0.f;
    if (r < Rr && c < Cc) v = in[((size_t)b * Rr + r) * Cc + c];
    tile[ty + i * 8][tx] = v;
  }
  __syncthreads();
#pragma unroll
  for (int i = 0; i < 4; i++) {
    int c = c0 + ty + i * 8, r = r0 + tx;
    if (c < Cpad && r < Rr) out[((size_t)b * Cpad + c) * Rr + r] = f2bf(tile[tx][ty + i * 8]);
  }
}

// ---------- prep: c[s][r] = sum_k mu[s][k] * Us[s][k][r] ----------
__global__ __launch_bounds__(64) void compute_c(const float* __restrict__ mu,
                                                const float* __restrict__ Us,
                                                float* __restrict__ cvec) {
  int s = blockIdx.x >> 6, r = blockIdx.x & 63, t = threadIdx.x;
  float acc = 0.f;
#pragma unroll
  for (int k = t; k < H; k += 64) acc += mu[s * H + k] * Us[((size_t)s * H + k) * NR + r];
#pragma unroll
  for (int m = 32; m; m >>= 1) acc += __shfl_xor(acc, m, 64);
  if (t == 0) cvec[blockIdx.x] = acc;
}

// ---------- routing (unchanged from R4, known-good): alphaT[s][n] ----------
__device__ __forceinline__ void stage32r(const u16* __restrict__ g, u16* l, int wave, int lane) {
#pragma unroll
  for (int i = 0; i < 8; i++) {
    int r = wave * 8 + i;
    gload16(g + (size_t)r * 512 + (size_t)((lane ^ (r & 7)) * 8), l + r * 512);
  }
}

__global__ __launch_bounds__(256, 2) void routing(
    const float* __restrict__ enc, const u16* __restrict__ UcatT,
    const float* __restrict__ cvec, float* __restrict__ alphT) {
  __shared__ __align__(16) u16 Wst[2][32 * 512];
  __shared__ float distS[NS][64];

  const int tid = threadIdx.x;
  const int wave = tid >> 6, lane = tid & 63;
  const int lnm = lane & 15, lnq = lane >> 4;
  const int row0 = blockIdx.x * 64;

  bf16x8 afrag[16];
  {
    const float* rp = enc + (size_t)(row0 + wave * 16 + lnm) * H + lnq * 8;
#pragma unroll
    for (int ks = 0; ks < 16; ks++) {
      float4 x0 = *(const float4*)(rp + ks * 32);
      float4 x1 = *(const float4*)(rp + ks * 32 + 4);
      bf16x8 a;
      a[0] = (__bf16)x0.x; a[1] = (__bf16)x0.y; a[2] = (__bf16)x0.z; a[3] = (__bf16)x0.w;
      a[4] = (__bf16)x1.x; a[5] = (__bf16)x1.y; a[6] = (__bf16)x1.z; a[7] = (__bf16)x1.w;
      afrag[ks] = a;
    }
  }

  stage32r(UcatT, Wst[0], wave, lane);
  float dsq[4] = {0.f, 0.f, 0.f, 0.f};
#pragma unroll 1
  for (int q = 0; q < 16; q++) {
    int s = q >> 1, half = q & 1;
    __syncthreads();
    if (q < 15) stage32r(UcatT + (size_t)(q + 1) * 32 * 512, Wst[(q + 1) & 1], wave, lane);
    const u16* buf = Wst[q & 1];
    f32x4 acc[2] = {};
#pragma unroll
    for (int ks = 0; ks < 16; ks++) {
      int uu = ((ks * 4 + lnq) ^ (lnm & 7)) * 8;
      bf16x8 b0 = *(const bf16x8*)&buf[lnm * 512 + uu];
      bf16x8 b1v = *(const bf16x8*)&buf[(16 + lnm) * 512 + uu];
      acc[0] = __builtin_amdgcn_mfma_f32_16x16x32_bf16(afrag[ks], b0, acc[0], 0, 0, 0);
      acc[1] = __builtin_amdgcn_mfma_f32_16x16x32_bf16(afrag[ks], b1v, acc[1], 0, 0, 0);
    }
#pragma unroll
    for (int ct = 0; ct < 2; ct++) {
      float cv = cvec[s * 64 + half * 32 + ct * 16 + lnm];
#pragma unroll
      for (int g = 0; g < 4; g++) { float d = acc[ct][g] - cv; dsq[g] += d * d; }
    }
    if (half == 1) {
#pragma unroll
      for (int m = 1; m < 16; m <<= 1) {
#pragma unroll
        for (int g = 0; g < 4; g++) dsq[g] += __shfl_xor(dsq[g], m, 16);
      }
      if (lnm == 0) {
#pragma unroll
        for (int g = 0; g < 4; g++) distS[s][wave * 16 + lnq * 4 + g] = sqrtf(dsq[g]);
      }
#pragma unroll
      for (int g = 0; g < 4; g++) dsq[g] = 0.f;
    }
  }
  __syncthreads();
  if (tid < 64) {
    float dmin = distS[0][tid];
#pragma unroll
    for (int s = 1; s < NS; s++) dmin = fminf(dmin, distS[s][tid]);
    float den = 0.f, e[NS];
#pragma unroll
    for (int s = 0; s < NS; s++) { e[s] = __expf(dmin - distS[s][tid]); den += e[s]; }
    float inv = 1.f / den;
#pragma unroll
    for (int s = 0; s < NS; s++) alphT[(size_t)s * NROWS + row0 + tid] = e[s] * inv;
  }
}

// ---------- main classifier ----------
// 512 blocks = 128 row-blocks (256 rows) x 4 source-groups (2 sources each)
// 4 waves x 64 rows; GEMM1 = 32x32x16 with A=weights(LDS), B=enc(regs, 2 tiles)
// chunks: 32 wcols x 256 K (16 KB), double-buffered async, 1 barrier/chunk
#define H1STR 36   // u16 stride of h1c rows (72 B, 8B-aligned)

__device__ __forceinline__ void stageW(const u16* __restrict__ g, u16* l, int wave, int lane) {
  // 32 rows x 256 u16 (512B); global row stride 512 u16; 2 rows per gload16
  const int half = lane >> 5;
#pragma unroll
  for (int i = 0; i < 4; i++) {
    int rbase = wave * 8 + i * 2;
    int r = rbase + half;
    int unit = (lane & 31) ^ (r & 7);   // XOR-swizzled 16B unit within row
    gload16(g + (size_t)r * 512 + unit * 8, l + rbase * 256);
  }
}

template <int KH>
__device__ __forceinline__ void gemm1_half(const u16* __restrict__ buf,
                                           const bf16x8 (&ef)[2][32],
                                           int lane, f32x16* acc) {
  const int half = lane >> 5, r31 = lane & 31, rx = r31 & 7;
  const u16* rowp = buf + r31 * 256;
#pragma unroll
  for (int ks = 0; ks < 16; ks++) {
    bf16x8 a = *(const bf16x8*)&rowp[(((ks * 2 + half) ^ rx) * 8)];
    acc[0] = __builtin_amdgcn_mfma_f32_32x32x16_bf16(a, ef[0][KH * 16 + ks], acc[0], 0, 0, 0);
    acc[1] = __builtin_amdgcn_mfma_f32_32x32x16_bf16(a, ef[1][KH * 16 + ks], acc[1], 0, 0, 0);
  }
}

__global__ __launch_bounds__(256, 3) void moe_main(
    const float* __restrict__ enc, const u16* __restrict__ W1T,
    const u16* __restrict__ W2T, const float* __restrict__ alphT,
    const float* __restrict__ b1g, const float* __restrict__ b2g,
    float* __restrict__ out) {
  __shared__ __align__(16) u16 Wst[2][32 * 256];   // 32768 B (2 x 16 KB)
  __shared__ __align__(16) u16 h1c[256 * H1STR];   // 18432 B
  __shared__ float alphS[2][256];                  // 2048 B   (total 53248 -> 3 blocks/CU)

  const int tid = threadIdx.x;
  const int wave = tid >> 6, lane = tid & 63;
  const int half = lane >> 5, l31 = lane & 31;
  const int lnm = lane & 15, lnq = lane >> 4;
  const int rb = blockIdx.x >> 2, sg = blockIdx.x & 3;
  const int row0 = rb * 256, sbase = sg * 2;

  // stage alphas for this block's rows & 2 sources
#pragma unroll
  for (int i = 0; i < 2; i++) {
    int u = tid + i * 256, j = u >> 8, r = u & 255;
    alphS[j][r] = alphT[(size_t)(sbase + j) * NROWS + row0 + r];
  }

  // enc B-fragments: h0 = relu(enc), 2 n-tiles x 32 rows, full K=512 in regs
  bf16x8 efrag[2][32];
#pragma unroll
  for (int nt = 0; nt < 2; nt++) {
    const float* rp = enc + (size_t)(row0 + wave * 64 + nt * 32 + l31) * H;
#pragma unroll
    for (int ksg = 0; ksg < 32; ksg++) {
      const float* p = rp + ksg * 16 + half * 8;
      float4 x0 = *(const float4*)(p);
      float4 x1 = *(const float4*)(p + 4);
      bf16x8 a;
      a[0] = (__bf16)fmaxf(x0.x, 0.f); a[1] = (__bf16)fmaxf(x0.y, 0.f);
      a[2] = (__bf16)fmaxf(x0.z, 0.f); a[3] = (__bf16)fmaxf(x0.w, 0.f);
      a[4] = (__bf16)fmaxf(x1.x, 0.f); a[5] = (__bf16)fmaxf(x1.y, 0.f);
      a[6] = (__bf16)fmaxf(x1.z, 0.f); a[7] = (__bf16)fmaxf(x1.w, 0.f);
      efrag[nt][ksg] = a;
    }
  }

  const f32x16 zero16 = {};
  f32x16 acc[2];
  f32x4 oacc[4] = {};
  float fin[4][4] = {};

  stageW(W1T + (size_t)sbase * 512 * 512, Wst[0], wave, lane);
#pragma unroll 1
  for (int q = 0; q < 64; q++) {
    const int j = q >> 5, wc = (q >> 1) & 15, kh = q & 1;
    const int s = sbase + j;
    __syncthreads();                     // drains buf[q&1] loads; buf[(q+1)&1] free
    if (q < 63) {
      const int t = q + 1;
      const u16* nb = W1T +
          ((size_t)((sbase + (t >> 5)) * 512 + ((t >> 1) & 15) * 32)) * 512 + (t & 1) * 256;
      stageW(nb, Wst[t & 1], wave, lane);   // async, overlaps compute below
    }
    const u16* buf = Wst[q & 1];
    if (kh == 0) {
      acc[0] = zero16; acc[1] = zero16;
      gemm1_half<0>(buf, efrag, lane, acc);
    } else {
      gemm1_half<1>(buf, efrag, lane, acc);
      // ---- epilogue: h1 = relu(acc + b1) -> wave-private h1c rows (bf16) ----
#pragma unroll
      for (int rq = 0; rq < 4; rq++) {
        float4 bq = *(const float4*)&b1g[s * H + wc * 32 + 8 * rq + 4 * half];
#pragma unroll
        for (int nt = 0; nt < 2; nt++) {
          int row = wave * 64 + nt * 32 + l31;
          union { u16 u[4]; uint2 v; } pk;
          pk.u[0] = f2bf(fmaxf(acc[nt][rq * 4 + 0] + bq.x, 0.f));
          pk.u[1] = f2bf(fmaxf(acc[nt][rq * 4 + 1] + bq.y, 0.f));
          pk.u[2] = f2bf(fmaxf(acc[nt][rq * 4 + 2] + bq.z, 0.f));
          pk.u[3] = f2bf(fmaxf(acc[nt][rq * 4 + 3] + bq.w, 0.f));
          *(uint2*)&h1c[row * H1STR + 8 * rq + 4 * half] = pk.v;
        }
      }
      // ---- GEMM2 partial over this 32-wcol window ----
      bf16x8 bw = *(const bf16x8*)&W2T[((size_t)s * 16 + lnm) * H + wc * 32 + lnq * 8];
#pragma unroll
      for (int mt = 0; mt < 4; mt++) {
        union { uint2 h[2]; bf16x8 v; } a2;
        const u16* ap = &h1c[(wave * 64 + mt * 16 + lnm) * H1STR + lnq * 8];
        a2.h[0] = *(const uint2*)(ap);
        a2.h[1] = *(const uint2*)(ap + 4);
        oacc[mt] = __builtin_amdgcn_mfma_f32_16x16x32_bf16(a2.v, bw, oacc[mt], 0, 0, 0);
      }
      if (wc == 15) {   // end of source: sigmoid + alpha-weighted accumulate
        float b2v = (lnm < NT) ? b2g[s * NT + lnm] : 0.f;
#pragma unroll
        for (int mt = 0; mt < 4; mt++) {
          float4 al = *(const float4*)&alphS[j][wave * 64 + mt * 16 + lnq * 4];
#pragma unroll
          for (int g = 0; g < 4; g++) {
            float pre = oacc[mt][g] + b2v;
            float sig = 1.f / (1.f + __expf(-pre));
            fin[mt][g] += ((const float*)&al)[g] * sig;
          }
          oacc[mt] = (f32x4){0.f, 0.f, 0.f, 0.f};
        }
      }
    }
  }
  // combine partials across the 4 source-groups
  if (lnm < NT) {
#pragma unroll
    for (int mt = 0; mt < 4; mt++) {
#pragma unroll
      for (int g = 0; g < 4; g++) {
        int rg = row0 + wave * 64 + mt * 16 + lnq * 4 + g;
        atomicAdd(&out[(size_t)rg * NT + lnm], fin[mt][g]);
      }
    }
  }
}

extern "C" void kernel_launch(void* const* d_in, const int* in_sizes, int n_in,
                              void* d_out, int out_size, void* d_ws, size_t ws_size,
                              hipStream_t stream) {
  const float* enc = (const float*)d_in[0];
  const float* mu  = (const float*)d_in[1];
  const float* Us  = (const float*)d_in[2];
  const float* W1  = (const float*)d_in[3];
  const float* b1  = (const float*)d_in[4];
  const float* W2  = (const float*)d_in[5];
  const float* b2  = (const float*)d_in[6];
  float* out = (float*)d_out;
  char* ws = (char*)d_ws;
  u16* W1T    = (u16*)(ws + WS_W1T);
  u16* UcatT  = (u16*)(ws + WS_UCT);
  u16* W2T    = (u16*)(ws + WS_W2T);
  float* cvec = (float*)(ws + WS_CVEC);
  float* alphT = (float*)(ws + WS_ALPH);

  dim3 tb(32, 8, 1);
  transpose_cast<<<dim3(16, 16, 8), tb, 0, stream>>>(W1, W1T, 512, 512, 512);
  transpose_cast<<<dim3(16, 2, 8),  tb, 0, stream>>>(Us, UcatT, 512, 64, 64);
  transpose_cast<<<dim3(16, 1, 8),  tb, 0, stream>>>(W2, W2T, 512, 12, 16);
  compute_c<<<512, 64, 0, stream>>>(mu, Us, cvec);
  routing<<<512, 256, 0, stream>>>(enc, UcatT, cvec, alphT);
  hipMemsetAsync(out, 0, (size_t)out_size * sizeof(float), stream);
  moe_main<<<512, 256, 0, stream>>>(enc, W1T, W2T, alphT, b1, b2, out);
}

// Round 6
// 882.050 us; speedup vs baseline: 1.0771x; 1.0771x over previous
//
#include <hip/hip_runtime.h>
#include <hip/hip_bf16.h>

typedef unsigned short u16;
typedef __bf16 bf16x8 __attribute__((ext_vector_type(8)));
typedef float f32x4 __attribute__((ext_vector_type(4)));

#define NROWS 32768
#define H 512
#define NS 8
#define NR 64
#define NT 12

// workspace layout (bytes)
#define WS_W1T   0            // [8][512 n][512 k] bf16 = 4194304
#define WS_UCT   4194304      // [512 r][512 k] bf16    = 524288
#define WS_W2T   4718592      // [8][16 t][512 k] bf16  = 131072
#define WS_CVEC  4849664      // [8][64] f32            = 2048
#define WS_ALPH  4851712      // [8][32768] f32         = 1048576

union BFU { __bf16 h; u16 u; };
__device__ __forceinline__ u16 f2bf(float v) { BFU b; b.h = (__bf16)v; return b.u; }

__device__ __forceinline__ void gload16(const u16* g, u16* l) {
  __builtin_amdgcn_global_load_lds(
      (const __attribute__((address_space(1))) unsigned int*)g,
      (__attribute__((address_space(3))) unsigned int*)l, 16, 0, 0);
}

// ---------- prep: batched transpose + cast to bf16 ----------
__global__ __launch_bounds__(256) void transpose_cast(const float* __restrict__ in,
    u16* __restrict__ out, int Rr, int Cc, int Cpad) {
  __shared__ float tile[32][33];
  int b = blockIdx.z, r0 = blockIdx.x * 32, c0 = blockIdx.y * 32;
  int tx = threadIdx.x, ty = threadIdx.y;
#pragma unroll
  for (int i = 0; i < 4; i++) {
    int r = r0 + ty + i * 8, c = c0 + tx;
    float v = 0.f;
    if (r < Rr && c < Cc) v = in[((size_t)b * Rr + r) * Cc + c];
    tile[ty + i * 8][tx] = v;
  }
  __syncthreads();
#pragma unroll
  for (int i = 0; i < 4; i++) {
    int c = c0 + ty + i * 8, r = r0 + tx;
    if (c < Cpad && r < Rr) out[((size_t)b * Cpad + c) * Rr + r] = f2bf(tile[tx][ty + i * 8]);
  }
}

// ---------- prep: c[s][r] = sum_k mu[s][k] * Us[s][k][r] ----------
__global__ __launch_bounds__(64) void compute_c(const float* __restrict__ mu,
                                                const float* __restrict__ Us,
                                                float* __restrict__ cvec) {
  int s = blockIdx.x >> 6, r = blockIdx.x & 63, t = threadIdx.x;
  float acc = 0.f;
#pragma unroll
  for (int k = t; k < H; k += 64) acc += mu[s * H + k] * Us[((size_t)s * H + k) * NR + r];
#pragma unroll
  for (int m = 32; m; m >>= 1) acc += __shfl_xor(acc, m, 64);
  if (t == 0) cvec[blockIdx.x] = acc;
}

// ---------- routing (R4 version, known-good): alphaT[s][n] ----------
__device__ __forceinline__ void stage32r(const u16* __restrict__ g, u16* l, int wave, int lane) {
#pragma unroll
  for (int i = 0; i < 8; i++) {
    int r = wave * 8 + i;
    gload16(g + (size_t)r * 512 + (size_t)((lane ^ (r & 7)) * 8), l + r * 512);
  }
}

__global__ __launch_bounds__(256, 2) void routing(
    const float* __restrict__ enc, const u16* __restrict__ UcatT,
    const float* __restrict__ cvec, float* __restrict__ alphT) {
  __shared__ __align__(16) u16 Wst[2][32 * 512];
  __shared__ float distS[NS][64];

  const int tid = threadIdx.x;
  const int wave = tid >> 6, lane = tid & 63;
  const int lnm = lane & 15, lnq = lane >> 4;
  const int row0 = blockIdx.x * 64;

  bf16x8 afrag[16];
  {
    const float* rp = enc + (size_t)(row0 + wave * 16 + lnm) * H + lnq * 8;
#pragma unroll
    for (int ks = 0; ks < 16; ks++) {
      float4 x0 = *(const float4*)(rp + ks * 32);
      float4 x1 = *(const float4*)(rp + ks * 32 + 4);
      bf16x8 a;
      a[0] = (__bf16)x0.x; a[1] = (__bf16)x0.y; a[2] = (__bf16)x0.z; a[3] = (__bf16)x0.w;
      a[4] = (__bf16)x1.x; a[5] = (__bf16)x1.y; a[6] = (__bf16)x1.z; a[7] = (__bf16)x1.w;
      afrag[ks] = a;
    }
  }

  stage32r(UcatT, Wst[0], wave, lane);
  float dsq[4] = {0.f, 0.f, 0.f, 0.f};
#pragma unroll 1
  for (int q = 0; q < 16; q++) {
    int s = q >> 1, half = q & 1;
    __syncthreads();
    if (q < 15) stage32r(UcatT + (size_t)(q + 1) * 32 * 512, Wst[(q + 1) & 1], wave, lane);
    const u16* buf = Wst[q & 1];
    f32x4 acc[2] = {};
#pragma unroll
    for (int ks = 0; ks < 16; ks++) {
      int uu = ((ks * 4 + lnq) ^ (lnm & 7)) * 8;
      bf16x8 b0 = *(const bf16x8*)&buf[lnm * 512 + uu];
      bf16x8 b1v = *(const bf16x8*)&buf[(16 + lnm) * 512 + uu];
      acc[0] = __builtin_amdgcn_mfma_f32_16x16x32_bf16(afrag[ks], b0, acc[0], 0, 0, 0);
      acc[1] = __builtin_amdgcn_mfma_f32_16x16x32_bf16(afrag[ks], b1v, acc[1], 0, 0, 0);
    }
#pragma unroll
    for (int ct = 0; ct < 2; ct++) {
      float cv = cvec[s * 64 + half * 32 + ct * 16 + lnm];
#pragma unroll
      for (int g = 0; g < 4; g++) { float d = acc[ct][g] - cv; dsq[g] += d * d; }
    }
    if (half == 1) {
#pragma unroll
      for (int m = 1; m < 16; m <<= 1) {
#pragma unroll
        for (int g = 0; g < 4; g++) dsq[g] += __shfl_xor(dsq[g], m, 16);
      }
      if (lnm == 0) {
#pragma unroll
        for (int g = 0; g < 4; g++) distS[s][wave * 16 + lnq * 4 + g] = sqrtf(dsq[g]);
      }
#pragma unroll
      for (int g = 0; g < 4; g++) dsq[g] = 0.f;
    }
  }
  __syncthreads();
  if (tid < 64) {
    float dmin = distS[0][tid];
#pragma unroll
    for (int s = 1; s < NS; s++) dmin = fminf(dmin, distS[s][tid]);
    float den = 0.f, e[NS];
#pragma unroll
    for (int s = 0; s < NS; s++) { e[s] = __expf(dmin - distS[s][tid]); den += e[s]; }
    float inv = 1.f / den;
#pragma unroll
    for (int s = 0; s < NS; s++) alphT[(size_t)s * NROWS + row0 + tid] = e[s] * inv;
  }
}

// ---------- main classifier ----------
// Grid: 1024 blocks = 256 row-blocks (128 rows) x 4 source-groups (2 sources each).
// 4 waves x 2 enc n-tiles (32 rows/wave). GEMM1: A = weights (LDS, 32wcolx256K
// dbuf chunks), B = enc regs (efrag = 128 VGPR). C-layout: enc-row in lanes,
// wcols in regs -> packed b64 h1 epilogue. 1 barrier/chunk, async stage.
#define H1STR 40   // u16 row stride (80 B): bank-uniform, 16B-aligned b128 reads

__device__ __forceinline__ void stageW16(const u16* __restrict__ g, u16* l, int tid) {
  // 32 rows x 256 u16 (512 B/row); global row stride 512 u16; XOR-swizzled units
#pragma unroll
  for (int i = 0; i < 4; i++) {
    int flat = tid + i * 256;          // 0..1023, lane-linear LDS placement
    int r = flat >> 5, u = flat & 31;
    gload16(g + (size_t)r * 512 + (u ^ (r & 7)) * 8, l + flat * 8);
  }
}

__global__ __launch_bounds__(256, 3) void moe_main(
    const float* __restrict__ enc, const u16* __restrict__ W1T,
    const u16* __restrict__ W2T, const float* __restrict__ alphT,
    const float* __restrict__ b1g, const float* __restrict__ b2g,
    float* __restrict__ out) {
  __shared__ __align__(16) u16 Wst[2][32 * 256];   // 32768 B
  __shared__ __align__(16) u16 h1c[128 * H1STR];   // 10240 B
  __shared__ float alphS[2][128];                  // 1024 B  (total 44032 -> 3 blocks/CU)

  const int tid = threadIdx.x;
  const int wave = tid >> 6, lane = tid & 63;
  const int lnm = lane & 15, lnq = lane >> 4;
  const int rb = blockIdx.x & 255, sg = blockIdx.x >> 8;
  const int row0 = rb * 128, sbase = sg * 2;

  { int j = tid >> 7, r = tid & 127;
    alphS[j][r] = alphT[(size_t)(sbase + j) * NROWS + row0 + r]; }

  // B-operand fragments: h0 = relu(enc), 2 n-tiles x 16 k-steps (128 VGPR)
  bf16x8 efrag[2][16];
#pragma unroll
  for (int t = 0; t < 2; t++) {
    const float* rp = enc + (size_t)(row0 + wave * 32 + t * 16 + lnm) * H + lnq * 8;
#pragma unroll
    for (int ks = 0; ks < 16; ks++) {
      float4 x0 = *(const float4*)(rp + ks * 32);
      float4 x1 = *(const float4*)(rp + ks * 32 + 4);
      bf16x8 a;
      a[0] = (__bf16)fmaxf(x0.x, 0.f); a[1] = (__bf16)fmaxf(x0.y, 0.f);
      a[2] = (__bf16)fmaxf(x0.z, 0.f); a[3] = (__bf16)fmaxf(x0.w, 0.f);
      a[4] = (__bf16)fmaxf(x1.x, 0.f); a[5] = (__bf16)fmaxf(x1.y, 0.f);
      a[6] = (__bf16)fmaxf(x1.z, 0.f); a[7] = (__bf16)fmaxf(x1.w, 0.f);
      efrag[t][ks] = a;
    }
  }

  stageW16(W1T + (size_t)sbase * 512 * 512, Wst[0], tid);
  f32x4 acc[2][2];      // [enc-tile t][wcol-tile ct]
  f32x4 oacc[2] = {};   // GEMM2 accumulators per enc-tile
#pragma unroll 1
  for (int q = 0; q < 64; q++) {
    const int j = q >> 5, ch = (q >> 1) & 15, kh = q & 1;
    const int s = sbase + j;
    __syncthreads();                   // drains buf[q&1]'s loads; buf[(q+1)&1] free
    if (q < 63) {
      const int t = q + 1;
      const u16* nb = W1T +
          ((size_t)((sbase + (t >> 5)) * 512 + ((t >> 1) & 15) * 32)) * 512 + (t & 1) * 256;
      stageW16(nb, Wst[t & 1], tid);   // async, overlaps compute below
    }
    const u16* buf = Wst[q & 1];
    if (kh == 0) {
#pragma unroll
      for (int t = 0; t < 2; t++) { acc[t][0] = (f32x4){0,0,0,0}; acc[t][1] = (f32x4){0,0,0,0}; }
    }
#pragma unroll
    for (int ks = 0; ks < 8; ks++) {
      const int uu = ((ks * 4 + lnq) ^ (lnm & 7)) * 8;
      bf16x8 w0 = *(const bf16x8*)&buf[lnm * 256 + uu];
      bf16x8 w1 = *(const bf16x8*)&buf[(16 + lnm) * 256 + uu];
#pragma unroll
      for (int t = 0; t < 2; t++) {
        acc[t][0] = __builtin_amdgcn_mfma_f32_16x16x32_bf16(w0, efrag[t][kh * 8 + ks], acc[t][0], 0, 0, 0);
        acc[t][1] = __builtin_amdgcn_mfma_f32_16x16x32_bf16(w1, efrag[t][kh * 8 + ks], acc[t][1], 0, 0, 0);
      }
    }
    if (kh == 1) {
      // epilogue: h1 = relu(acc + b1); lane holds 4 consecutive wcols -> b64 writes
#pragma unroll
      for (int ct = 0; ct < 2; ct++) {
        float4 bq = *(const float4*)&b1g[s * H + ch * 32 + ct * 16 + lnq * 4];
#pragma unroll
        for (int t = 0; t < 2; t++) {
          union { u16 u[4]; uint2 v; } pk;
          pk.u[0] = f2bf(fmaxf(acc[t][ct][0] + bq.x, 0.f));
          pk.u[1] = f2bf(fmaxf(acc[t][ct][1] + bq.y, 0.f));
          pk.u[2] = f2bf(fmaxf(acc[t][ct][2] + bq.z, 0.f));
          pk.u[3] = f2bf(fmaxf(acc[t][ct][3] + bq.w, 0.f));
          *(uint2*)&h1c[(wave * 32 + t * 16 + lnm) * H1STR + ct * 16 + lnq * 4] = pk.v;
        }
      }
      // GEMM2 partial over this 32-wcol window (wave-private rows, no barrier)
      bf16x8 bw = *(const bf16x8*)&W2T[((size_t)s * 16 + lnm) * H + ch * 32 + lnq * 8];
#pragma unroll
      for (int t = 0; t < 2; t++) {
        bf16x8 a2 = *(const bf16x8*)&h1c[(wave * 32 + t * 16 + lnm) * H1STR + lnq * 8];
        oacc[t] = __builtin_amdgcn_mfma_f32_16x16x32_bf16(a2, bw, oacc[t], 0, 0, 0);
      }
      if (ch == 15) {   // end of source: sigmoid + alpha-weight, atomic combine
        float b2v = (lnm < NT) ? b2g[s * NT + lnm] : 0.f;
#pragma unroll
        for (int t = 0; t < 2; t++) {
#pragma unroll
          for (int g = 0; g < 4; g++) {
            float sig = 1.f / (1.f + __expf(-(oacc[t][g] + b2v)));
            float av = alphS[j][wave * 32 + t * 16 + lnq * 4 + g];
            if (lnm < NT) {
              int rg = row0 + wave * 32 + t * 16 + lnq * 4 + g;
              atomicAdd(&out[(size_t)rg * NT + lnm], av * sig);
            }
          }
          oacc[t] = (f32x4){0.f, 0.f, 0.f, 0.f};
        }
      }
    }
  }
}

extern "C" void kernel_launch(void* const* d_in, const int* in_sizes, int n_in,
                              void* d_out, int out_size, void* d_ws, size_t ws_size,
                              hipStream_t stream) {
  const float* enc = (const float*)d_in[0];
  const float* mu  = (const float*)d_in[1];
  const float* Us  = (const float*)d_in[2];
  const float* W1  = (const float*)d_in[3];
  const float* b1  = (const float*)d_in[4];
  const float* W2  = (const float*)d_in[5];
  const float* b2  = (const float*)d_in[6];
  float* out = (float*)d_out;
  char* ws = (char*)d_ws;
  u16* W1T    = (u16*)(ws + WS_W1T);
  u16* UcatT  = (u16*)(ws + WS_UCT);
  u16* W2T    = (u16*)(ws + WS_W2T);
  float* cvec = (float*)(ws + WS_CVEC);
  float* alphT = (float*)(ws + WS_ALPH);

  dim3 tb(32, 8, 1);
  transpose_cast<<<dim3(16, 16, 8), tb, 0, stream>>>(W1, W1T, 512, 512, 512);
  transpose_cast<<<dim3(16, 2, 8),  tb, 0, stream>>>(Us, UcatT, 512, 64, 64);
  transpose_cast<<<dim3(16, 1, 8),  tb, 0, stream>>>(W2, W2T, 512, 12, 16);
  compute_c<<<512, 64, 0, stream>>>(mu, Us, cvec);
  routing<<<512, 256, 0, stream>>>(enc, UcatT, cvec, alphT);
  hipMemsetAsync(out, 0, (size_t)out_size * sizeof(float), stream);
  moe_main<<<1024, 256, 0, stream>>>(enc, W1T, W2T, alphT, b1, b2, out);
}

// Round 7
// 383.480 us; speedup vs baseline: 2.4774x; 2.3001x over previous
//
#include <hip/hip_runtime.h>
#include <hip/hip_bf16.h>

typedef unsigned short u16;
typedef __bf16 bf16x8 __attribute__((ext_vector_type(8)));
typedef float f32x4 __attribute__((ext_vector_type(4)));

#define NROWS 32768
#define H 512
#define NS 8
#define NR 64
#define NT 12

// workspace layout (bytes)
#define WS_W1T   0            // [8][512 n][512 k] bf16 = 4194304
#define WS_UCT   4194304      // [512 r][512 k] bf16    = 524288
#define WS_W2T   4718592      // [8][16 t][512 k] bf16  = 131072
#define WS_CVEC  4849664      // [8][64] f32            = 2048
#define WS_ALPH  4851712      // [8][32768] f32         = 1048576

#define TM 3                  // m-tiles per wave (48 rows/wave, 192 rows/block)
#define RPB 192
#define NRB 171               // ceil(32768/192)

union BFU { __bf16 h; u16 u; };
__device__ __forceinline__ u16 f2bf(float v) { BFU b; b.h = (__bf16)v; return b.u; }

__device__ __forceinline__ void gload16(const u16* g, u16* l) {
  __builtin_amdgcn_global_load_lds(
      (const __attribute__((address_space(1))) unsigned int*)g,
      (__attribute__((address_space(3))) unsigned int*)l, 16, 0, 0);
}

// ---------- prep: batched transpose + cast to bf16 ----------
__global__ __launch_bounds__(256) void transpose_cast(const float* __restrict__ in,
    u16* __restrict__ out, int Rr, int Cc, int Cpad) {
  __shared__ float tile[32][33];
  int b = blockIdx.z, r0 = blockIdx.x * 32, c0 = blockIdx.y * 32;
  int tx = threadIdx.x, ty = threadIdx.y;
#pragma unroll
  for (int i = 0; i < 4; i++) {
    int r = r0 + ty + i * 8, c = c0 + tx;
    float v = 0.f;
    if (r < Rr && c < Cc) v = in[((size_t)b * Rr + r) * Cc + c];
    tile[ty + i * 8][tx] = v;
  }
  __syncthreads();
#pragma unroll
  for (int i = 0; i < 4; i++) {
    int c = c0 + ty + i * 8, r = r0 + tx;
    if (c < Cpad && r < Rr) out[((size_t)b * Cpad + c) * Rr + r] = f2bf(tile[tx][ty + i * 8]);
  }
}

// ---------- prep: c[s][r] = sum_k mu[s][k] * Us[s][k][r] ----------
__global__ __launch_bounds__(64) void compute_c(const float* __restrict__ mu,
                                                const float* __restrict__ Us,
                                                float* __restrict__ cvec) {
  int s = blockIdx.x >> 6, r = blockIdx.x & 63, t = threadIdx.x;
  float acc = 0.f;
#pragma unroll
  for (int k = t; k < H; k += 64) acc += mu[s * H + k] * Us[((size_t)s * H + k) * NR + r];
#pragma unroll
  for (int m = 32; m; m >>= 1) acc += __shfl_xor(acc, m, 64);
  if (t == 0) cvec[blockIdx.x] = acc;
}

// ---------- routing (R4 version, known-good): alphaT[s][n] ----------
__device__ __forceinline__ void stage32r(const u16* __restrict__ g, u16* l, int wave, int lane) {
#pragma unroll
  for (int i = 0; i < 8; i++) {
    int r = wave * 8 + i;
    gload16(g + (size_t)r * 512 + (size_t)((lane ^ (r & 7)) * 8), l + r * 512);
  }
}

__global__ __launch_bounds__(256, 2) void routing(
    const float* __restrict__ enc, const u16* __restrict__ UcatT,
    const float* __restrict__ cvec, float* __restrict__ alphT) {
  __shared__ __align__(16) u16 Wst[2][32 * 512];
  __shared__ float distS[NS][64];

  const int tid = threadIdx.x;
  const int wave = tid >> 6, lane = tid & 63;
  const int lnm = lane & 15, lnq = lane >> 4;
  const int row0 = blockIdx.x * 64;

  bf16x8 afrag[16];
  {
    const float* rp = enc + (size_t)(row0 + wave * 16 + lnm) * H + lnq * 8;
#pragma unroll
    for (int ks = 0; ks < 16; ks++) {
      float4 x0 = *(const float4*)(rp + ks * 32);
      float4 x1 = *(const float4*)(rp + ks * 32 + 4);
      bf16x8 a;
      a[0] = (__bf16)x0.x; a[1] = (__bf16)x0.y; a[2] = (__bf16)x0.z; a[3] = (__bf16)x0.w;
      a[4] = (__bf16)x1.x; a[5] = (__bf16)x1.y; a[6] = (__bf16)x1.z; a[7] = (__bf16)x1.w;
      afrag[ks] = a;
    }
  }

  stage32r(UcatT, Wst[0], wave, lane);
  float dsq[4] = {0.f, 0.f, 0.f, 0.f};
#pragma unroll 1
  for (int q = 0; q < 16; q++) {
    int s = q >> 1, half = q & 1;
    __syncthreads();
    if (q < 15) stage32r(UcatT + (size_t)(q + 1) * 32 * 512, Wst[(q + 1) & 1], wave, lane);
    const u16* buf = Wst[q & 1];
    f32x4 acc[2] = {};
#pragma unroll
    for (int ks = 0; ks < 16; ks++) {
      int uu = ((ks * 4 + lnq) ^ (lnm & 7)) * 8;
      bf16x8 b0 = *(const bf16x8*)&buf[lnm * 512 + uu];
      bf16x8 b1v = *(const bf16x8*)&buf[(16 + lnm) * 512 + uu];
      acc[0] = __builtin_amdgcn_mfma_f32_16x16x32_bf16(afrag[ks], b0, acc[0], 0, 0, 0);
      acc[1] = __builtin_amdgcn_mfma_f32_16x16x32_bf16(afrag[ks], b1v, acc[1], 0, 0, 0);
    }
#pragma unroll
    for (int ct = 0; ct < 2; ct++) {
      float cv = cvec[s * 64 + half * 32 + ct * 16 + lnm];
#pragma unroll
      for (int g = 0; g < 4; g++) { float d = acc[ct][g] - cv; dsq[g] += d * d; }
    }
    if (half == 1) {
#pragma unroll
      for (int m = 1; m < 16; m <<= 1) {
#pragma unroll
        for (int g = 0; g < 4; g++) dsq[g] += __shfl_xor(dsq[g], m, 16);
      }
      if (lnm == 0) {
#pragma unroll
        for (int g = 0; g < 4; g++) distS[s][wave * 16 + lnq * 4 + g] = sqrtf(dsq[g]);
      }
#pragma unroll
      for (int g = 0; g < 4; g++) dsq[g] = 0.f;
    }
  }
  __syncthreads();
  if (tid < 64) {
    float dmin = distS[0][tid];
#pragma unroll
    for (int s = 1; s < NS; s++) dmin = fminf(dmin, distS[s][tid]);
    float den = 0.f, e[NS];
#pragma unroll
    for (int s = 0; s < NS; s++) { e[s] = __expf(dmin - distS[s][tid]); den += e[s]; }
    float inv = 1.f / den;
#pragma unroll
    for (int s = 0; s < NS; s++) alphT[(size_t)s * NROWS + row0 + tid] = e[s] * inv;
  }
}

// ---------- main classifier ----------
// Grid: 1368 blocks = 171 row-blocks (192 rows) x 8 sources (1 each).
// 4 waves x TM=3 enc tiles (48 rows/wave). GEMM1: A = weights (LDS, 32wcol x
// 256K dbuf chunks), B = enc regs (efrag[3][16] = 192 VGPR, ALL indices
// compile-time -> no scratch). C-layout: enc-row in lanes, wcols in regs.
#define H1STR 40   // u16 row stride (80 B)

__device__ __forceinline__ void stageW16(const u16* __restrict__ g, u16* l, int tid) {
  // 32 rows x 256 u16 (512 B/row); global row stride 512 u16; XOR-swizzled units
#pragma unroll
  for (int i = 0; i < 4; i++) {
    int flat = tid + i * 256;          // 0..1023
    int r = flat >> 5, u = flat & 31;
    gload16(g + (size_t)r * 512 + (u ^ (r & 7)) * 8, l + flat * 8);
  }
}

__global__ __launch_bounds__(256, 2) void moe_main(
    const float* __restrict__ enc, const u16* __restrict__ W1T,
    const u16* __restrict__ W2T, const float* __restrict__ alphT,
    const float* __restrict__ b1g, const float* __restrict__ b2g,
    float* __restrict__ out) {
  __shared__ __align__(16) u16 Wst[2][32 * 256];   // 32768 B
  __shared__ __align__(16) u16 h1c[RPB * H1STR];   // 15360 B
  __shared__ float alphS[RPB];                     // 768 B   (~48.9 KB total)

  const int tid = threadIdx.x;
  const int wave = tid >> 6, lane = tid & 63;
  const int lnm = lane & 15, lnq = lane >> 4;
  const int s = blockIdx.x & 7, rb = blockIdx.x >> 3;
  const int row0 = rb * RPB;

  if (tid < RPB) {
    int r = row0 + tid; if (r > NROWS - 1) r = NROWS - 1;
    alphS[tid] = alphT[(size_t)s * NROWS + r];
  }

  // B-operand fragments: h0 = relu(enc), TM tiles x 16 k-steps (192 VGPR)
  bf16x8 efrag[TM][16];
#pragma unroll
  for (int t = 0; t < TM; t++) {
    int r = row0 + wave * 48 + t * 16 + lnm; if (r > NROWS - 1) r = NROWS - 1;
    const float* rp = enc + (size_t)r * H + lnq * 8;
#pragma unroll
    for (int ks = 0; ks < 16; ks++) {
      float4 x0 = *(const float4*)(rp + ks * 32);
      float4 x1 = *(const float4*)(rp + ks * 32 + 4);
      bf16x8 a;
      a[0] = (__bf16)fmaxf(x0.x, 0.f); a[1] = (__bf16)fmaxf(x0.y, 0.f);
      a[2] = (__bf16)fmaxf(x0.z, 0.f); a[3] = (__bf16)fmaxf(x0.w, 0.f);
      a[4] = (__bf16)fmaxf(x1.x, 0.f); a[5] = (__bf16)fmaxf(x1.y, 0.f);
      a[6] = (__bf16)fmaxf(x1.z, 0.f); a[7] = (__bf16)fmaxf(x1.w, 0.f);
      efrag[t][ks] = a;
    }
  }

  const u16* W1s = W1T + (size_t)s * 512 * 512;
  stageW16(W1s, Wst[0], tid);          // chunk (wc=0, kh=0)
  f32x4 acc[TM][2];
  f32x4 oacc[TM] = {};
#pragma unroll 1
  for (int wc = 0; wc < 16; wc++) {
    // ======== kh = 0 (buf Wst[0]) ========
    __syncthreads();                    // drains Wst[0] loads; Wst[1] free
    stageW16(W1s + (size_t)wc * 32 * 512 + 256, Wst[1], tid);   // (wc, kh=1)
    {
      const u16* buf = Wst[0];
#pragma unroll
      for (int t = 0; t < TM; t++) { acc[t][0] = (f32x4){0,0,0,0}; acc[t][1] = (f32x4){0,0,0,0}; }
#pragma unroll
      for (int ks = 0; ks < 8; ks++) {
        const int uu = ((ks * 4 + lnq) ^ (lnm & 7)) * 8;
        bf16x8 w0 = *(const bf16x8*)&buf[lnm * 256 + uu];
        bf16x8 w1 = *(const bf16x8*)&buf[(16 + lnm) * 256 + uu];
#pragma unroll
        for (int t = 0; t < TM; t++) {
          acc[t][0] = __builtin_amdgcn_mfma_f32_16x16x32_bf16(w0, efrag[t][ks], acc[t][0], 0, 0, 0);
          acc[t][1] = __builtin_amdgcn_mfma_f32_16x16x32_bf16(w1, efrag[t][ks], acc[t][1], 0, 0, 0);
        }
      }
    }
    // ======== kh = 1 (buf Wst[1]) ========
    __syncthreads();                    // drains Wst[1] loads; Wst[0] free
    if (wc < 15) stageW16(W1s + (size_t)(wc + 1) * 32 * 512, Wst[0], tid);  // (wc+1, kh=0)
    {
      const u16* buf = Wst[1];
#pragma unroll
      for (int ks = 0; ks < 8; ks++) {
        const int uu = ((ks * 4 + lnq) ^ (lnm & 7)) * 8;
        bf16x8 w0 = *(const bf16x8*)&buf[lnm * 256 + uu];
        bf16x8 w1 = *(const bf16x8*)&buf[(16 + lnm) * 256 + uu];
#pragma unroll
        for (int t = 0; t < TM; t++) {
          acc[t][0] = __builtin_amdgcn_mfma_f32_16x16x32_bf16(w0, efrag[t][8 + ks], acc[t][0], 0, 0, 0);
          acc[t][1] = __builtin_amdgcn_mfma_f32_16x16x32_bf16(w1, efrag[t][8 + ks], acc[t][1], 0, 0, 0);
        }
      }
    }
    // ---- epilogue: h1 = relu(acc + b1) -> wave-private h1c rows (packed b64) ----
#pragma unroll
    for (int ct = 0; ct < 2; ct++) {
      float4 bq = *(const float4*)&b1g[s * H + wc * 32 + ct * 16 + lnq * 4];
#pragma unroll
      for (int t = 0; t < TM; t++) {
        union { u16 u[4]; uint2 v; } pk;
        pk.u[0] = f2bf(fmaxf(acc[t][ct][0] + bq.x, 0.f));
        pk.u[1] = f2bf(fmaxf(acc[t][ct][1] + bq.y, 0.f));
        pk.u[2] = f2bf(fmaxf(acc[t][ct][2] + bq.z, 0.f));
        pk.u[3] = f2bf(fmaxf(acc[t][ct][3] + bq.w, 0.f));
        *(uint2*)&h1c[(wave * 48 + t * 16 + lnm) * H1STR + ct * 16 + lnq * 4] = pk.v;
      }
    }
    // ---- GEMM2 partial over this 32-wcol window ----
    {
      bf16x8 bw = *(const bf16x8*)&W2T[((size_t)s * 16 + lnm) * H + wc * 32 + lnq * 8];
#pragma unroll
      for (int t = 0; t < TM; t++) {
        bf16x8 a2 = *(const bf16x8*)&h1c[(wave * 48 + t * 16 + lnm) * H1STR + lnq * 8];
        oacc[t] = __builtin_amdgcn_mfma_f32_16x16x32_bf16(a2, bw, oacc[t], 0, 0, 0);
      }
    }
  }
  // ---- sigmoid + alpha-weight, atomic combine (row-guarded for tail block) ----
  float b2v = (lnm < NT) ? b2g[s * NT + lnm] : 0.f;
#pragma unroll
  for (int t = 0; t < TM; t++) {
#pragma unroll
    for (int g = 0; g < 4; g++) {
      float sig = 1.f / (1.f + __expf(-(oacc[t][g] + b2v)));
      int rl = wave * 48 + t * 16 + lnq * 4 + g;
      int rg = row0 + rl;
      if (lnm < NT && rg < NROWS)
        atomicAdd(&out[(size_t)rg * NT + lnm], alphS[rl] * sig);
    }
  }
}

extern "C" void kernel_launch(void* const* d_in, const int* in_sizes, int n_in,
                              void* d_out, int out_size, void* d_ws, size_t ws_size,
                              hipStream_t stream) {
  const float* enc = (const float*)d_in[0];
  const float* mu  = (const float*)d_in[1];
  const float* Us  = (const float*)d_in[2];
  const float* W1  = (const float*)d_in[3];
  const float* b1  = (const float*)d_in[4];
  const float* W2  = (const float*)d_in[5];
  const float* b2  = (const float*)d_in[6];
  float* out = (float*)d_out;
  char* ws = (char*)d_ws;
  u16* W1T    = (u16*)(ws + WS_W1T);
  u16* UcatT  = (u16*)(ws + WS_UCT);
  u16* W2T    = (u16*)(ws + WS_W2T);
  float* cvec = (float*)(ws + WS_CVEC);
  float* alphT = (float*)(ws + WS_ALPH);

  dim3 tb(32, 8, 1);
  transpose_cast<<<dim3(16, 16, 8), tb, 0, stream>>>(W1, W1T, 512, 512, 512);
  transpose_cast<<<dim3(16, 2, 8),  tb, 0, stream>>>(Us, UcatT, 512, 64, 64);
  transpose_cast<<<dim3(16, 1, 8),  tb, 0, stream>>>(W2, W2T, 512, 12, 16);
  compute_c<<<512, 64, 0, stream>>>(mu, Us, cvec);
  routing<<<512, 256, 0, stream>>>(enc, UcatT, cvec, alphT);
  hipMemsetAsync(out, 0, (size_t)out_size * sizeof(float), stream);
  moe_main<<<NRB * 8, 256, 0, stream>>>(enc, W1T, W2T, alphT, b1, b2, out);
}

// Round 8
// 300.421 us; speedup vs baseline: 3.1623x; 1.2765x over previous
//
#include <hip/hip_runtime.h>
#include <hip/hip_bf16.h>

typedef unsigned short u16;
typedef __bf16 bf16x8 __attribute__((ext_vector_type(8)));
typedef float f32x4 __attribute__((ext_vector_type(4)));

#define NROWS 32768
#define H 512
#define NS 8
#define NR 64
#define NT 12

// workspace layout (bytes)
#define WS_W1T   0            // [8][512 n][512 k] bf16 = 4194304
#define WS_UCT   4194304      // [512 r][512 k] bf16    = 524288
#define WS_W2T   4718592      // [8][16 t][512 k] bf16  = 131072
#define WS_CVEC  4849664      // [8][64] f32            = 2048
#define WS_ALPH  4851712      // [8][32768] f32         = 1048576

union BFU { __bf16 h; u16 u; };
__device__ __forceinline__ u16 f2bf(float v) { BFU b; b.h = (__bf16)v; return b.u; }

__device__ __forceinline__ void gload16(const u16* g, u16* l) {
  __builtin_amdgcn_global_load_lds(
      (const __attribute__((address_space(1))) unsigned int*)g,
      (__attribute__((address_space(3))) unsigned int*)l, 16, 0, 0);
}

// ---------- prep: batched transpose + cast to bf16 ----------
__global__ __launch_bounds__(256) void transpose_cast(const float* __restrict__ in,
    u16* __restrict__ out, int Rr, int Cc, int Cpad) {
  __shared__ float tile[32][33];
  int b = blockIdx.z, r0 = blockIdx.x * 32, c0 = blockIdx.y * 32;
  int tx = threadIdx.x, ty = threadIdx.y;
#pragma unroll
  for (int i = 0; i < 4; i++) {
    int r = r0 + ty + i * 8, c = c0 + tx;
    float v = 0.f;
    if (r < Rr && c < Cc) v = in[((size_t)b * Rr + r) * Cc + c];
    tile[ty + i * 8][tx] = v;
  }
  __syncthreads();
#pragma unroll
  for (int i = 0; i < 4; i++) {
    int c = c0 + ty + i * 8, r = r0 + tx;
    if (c < Cpad && r < Rr) out[((size_t)b * Cpad + c) * Rr + r] = f2bf(tile[tx][ty + i * 8]);
  }
}

// ---------- prep: c[s][r] = sum_k mu[s][k] * Us[s][k][r] ----------
__global__ __launch_bounds__(64) void compute_c(const float* __restrict__ mu,
                                                const float* __restrict__ Us,
                                                float* __restrict__ cvec) {
  int s = blockIdx.x >> 6, r = blockIdx.x & 63, t = threadIdx.x;
  float acc = 0.f;
#pragma unroll
  for (int k = t; k < H; k += 64) acc += mu[s * H + k] * Us[((size_t)s * H + k) * NR + r];
#pragma unroll
  for (int m = 32; m; m >>= 1) acc += __shfl_xor(acc, m, 64);
  if (t == 0) cvec[blockIdx.x] = acc;
}

// ---------- routing (known-good): alphaT[s][n] ----------
__device__ __forceinline__ void stage32r(const u16* __restrict__ g, u16* l, int wave, int lane) {
#pragma unroll
  for (int i = 0; i < 8; i++) {
    int r = wave * 8 + i;
    gload16(g + (size_t)r * 512 + (size_t)((lane ^ (r & 7)) * 8), l + r * 512);
  }
}

__global__ __launch_bounds__(256, 2) void routing(
    const float* __restrict__ enc, const u16* __restrict__ UcatT,
    const float* __restrict__ cvec, float* __restrict__ alphT) {
  __shared__ __align__(16) u16 Wst[2][32 * 512];
  __shared__ float distS[NS][64];

  const int tid = threadIdx.x;
  const int wave = tid >> 6, lane = tid & 63;
  const int lnm = lane & 15, lnq = lane >> 4;
  const int row0 = blockIdx.x * 64;

  bf16x8 afrag[16];
  {
    const float* rp = enc + (size_t)(row0 + wave * 16 + lnm) * H + lnq * 8;
#pragma unroll
    for (int ks = 0; ks < 16; ks++) {
      float4 x0 = *(const float4*)(rp + ks * 32);
      float4 x1 = *(const float4*)(rp + ks * 32 + 4);
      bf16x8 a;
      a[0] = (__bf16)x0.x; a[1] = (__bf16)x0.y; a[2] = (__bf16)x0.z; a[3] = (__bf16)x0.w;
      a[4] = (__bf16)x1.x; a[5] = (__bf16)x1.y; a[6] = (__bf16)x1.z; a[7] = (__bf16)x1.w;
      afrag[ks] = a;
    }
  }

  stage32r(UcatT, Wst[0], wave, lane);
  float dsq[4] = {0.f, 0.f, 0.f, 0.f};
#pragma unroll 1
  for (int q = 0; q < 16; q++) {
    int s = q >> 1, half = q & 1;
    __syncthreads();
    if (q < 15) stage32r(UcatT + (size_t)(q + 1) * 32 * 512, Wst[(q + 1) & 1], wave, lane);
    const u16* buf = Wst[q & 1];
    f32x4 acc[2] = {};
#pragma unroll
    for (int ks = 0; ks < 16; ks++) {
      int uu = ((ks * 4 + lnq) ^ (lnm & 7)) * 8;
      bf16x8 b0 = *(const bf16x8*)&buf[lnm * 512 + uu];
      bf16x8 b1v = *(const bf16x8*)&buf[(16 + lnm) * 512 + uu];
      acc[0] = __builtin_amdgcn_mfma_f32_16x16x32_bf16(afrag[ks], b0, acc[0], 0, 0, 0);
      acc[1] = __builtin_amdgcn_mfma_f32_16x16x32_bf16(afrag[ks], b1v, acc[1], 0, 0, 0);
    }
#pragma unroll
    for (int ct = 0; ct < 2; ct++) {
      float cv = cvec[s * 64 + half * 32 + ct * 16 + lnm];
#pragma unroll
      for (int g = 0; g < 4; g++) { float d = acc[ct][g] - cv; dsq[g] += d * d; }
    }
    if (half == 1) {
#pragma unroll
      for (int m = 1; m < 16; m <<= 1) {
#pragma unroll
        for (int g = 0; g < 4; g++) dsq[g] += __shfl_xor(dsq[g], m, 16);
      }
      if (lnm == 0) {
#pragma unroll
        for (int g = 0; g < 4; g++) distS[s][wave * 16 + lnq * 4 + g] = sqrtf(dsq[g]);
      }
#pragma unroll
      for (int g = 0; g < 4; g++) dsq[g] = 0.f;
    }
  }
  __syncthreads();
  if (tid < 64) {
    float dmin = distS[0][tid];
#pragma unroll
    for (int s = 1; s < NS; s++) dmin = fminf(dmin, distS[s][tid]);
    float den = 0.f, e[NS];
#pragma unroll
    for (int s = 0; s < NS; s++) { e[s] = __expf(dmin - distS[s][tid]); den += e[s]; }
    float inv = 1.f / den;
#pragma unroll
    for (int s = 0; s < NS; s++) alphT[(size_t)s * NROWS + row0 + tid] = e[s] * inv;
  }
}

// ---------- main classifier ----------
// Grid: 512 blocks = 256 row-blocks (128 rows) x 2 source-groups (4 sources each).
// 4 waves x TM=2 enc tiles (32 rows/wave, 128 VGPR stationary — the proven fit).
// GEMM1: A = weights (LDS, 32wcol x 256K dbuf chunks), B = enc regs.
// All fragment indices compile-time. 1 barrier per 16 KB chunk.
#define H1STR 40   // u16 row stride (80 B)

__device__ __forceinline__ void stageW16(const u16* __restrict__ g, u16* l, int tid) {
  // 32 rows x 256 u16 (512 B/row); global row stride 512 u16; XOR-swizzled units
#pragma unroll
  for (int i = 0; i < 4; i++) {
    int flat = tid + i * 256;          // 0..1023
    int r = flat >> 5, u = flat & 31;
    gload16(g + (size_t)r * 512 + (u ^ (r & 7)) * 8, l + flat * 8);
  }
}

// chunk index q in [0,128): j=q>>5 (source), wc=(q>>1)&15, kh=q&1
__device__ __forceinline__ const u16* chunk_base(const u16* W1g, int q) {
  return W1g + ((size_t)(q >> 5) * 512 + ((q >> 1) & 15) * 32) * 512 + (q & 1) * 256;
}

__global__ __launch_bounds__(256, 2) void moe_main(
    const float* __restrict__ enc, const u16* __restrict__ W1T,
    const u16* __restrict__ W2T, const float* __restrict__ alphT,
    const float* __restrict__ b1g, const float* __restrict__ b2g,
    float* __restrict__ out) {
  __shared__ __align__(16) u16 Wst[2][32 * 256];   // 32768 B
  __shared__ __align__(16) u16 h1c[128 * H1STR];   // 10240 B
  __shared__ float alphS[4][128];                  // 2048 B  (total 45056 B)

  const int tid = threadIdx.x;
  const int wave = tid >> 6, lane = tid & 63;
  const int lnm = lane & 15, lnq = lane >> 4;
  const int rb = blockIdx.x >> 1, sg = blockIdx.x & 1;
  const int row0 = rb * 128, sbase = sg * 4;

#pragma unroll
  for (int i = 0; i < 2; i++) {
    int u = tid + i * 256, j = u >> 7, r = u & 127;
    alphS[j][r] = alphT[(size_t)(sbase + j) * NROWS + row0 + r];
  }

  // stationary B-operand: h0 = relu(enc) bf16, 2 tiles x 16 k-steps = 128 VGPR
  bf16x8 efrag[2][16];
#pragma unroll
  for (int t = 0; t < 2; t++) {
    const float* rp = enc + (size_t)(row0 + wave * 32 + t * 16 + lnm) * H + lnq * 8;
#pragma unroll
    for (int ks = 0; ks < 16; ks++) {
      float4 x0 = *(const float4*)(rp + ks * 32);
      float4 x1 = *(const float4*)(rp + ks * 32 + 4);
      bf16x8 a;
      a[0] = (__bf16)fmaxf(x0.x, 0.f); a[1] = (__bf16)fmaxf(x0.y, 0.f);
      a[2] = (__bf16)fmaxf(x0.z, 0.f); a[3] = (__bf16)fmaxf(x0.w, 0.f);
      a[4] = (__bf16)fmaxf(x1.x, 0.f); a[5] = (__bf16)fmaxf(x1.y, 0.f);
      a[6] = (__bf16)fmaxf(x1.z, 0.f); a[7] = (__bf16)fmaxf(x1.w, 0.f);
      efrag[t][ks] = a;
    }
  }

  const u16* W1g = W1T + (size_t)sbase * 512 * 512;
  stageW16(chunk_base(W1g, 0), Wst[0], tid);
  f32x4 acc[2][2];
  float fin[2][4] = {};
#pragma unroll 1
  for (int j = 0; j < 4; j++) {
    const int s = sbase + j;
    f32x4 oacc[2] = {};
#pragma unroll 1
    for (int wc = 0; wc < 16; wc++) {
      const int q = j * 32 + wc * 2;       // even -> lives in Wst[0]
      // ======== kh = 0 (Wst[0]) ========
      __syncthreads();                      // drains Wst[0]'s loads; Wst[1] free
      stageW16(chunk_base(W1g, q + 1), Wst[1], tid);
      {
        const u16* buf = Wst[0];
#pragma unroll
        for (int t = 0; t < 2; t++) { acc[t][0] = (f32x4){0,0,0,0}; acc[t][1] = (f32x4){0,0,0,0}; }
#pragma unroll
        for (int ks = 0; ks < 8; ks++) {
          const int uu = ((ks * 4 + lnq) ^ (lnm & 7)) * 8;
          bf16x8 w0 = *(const bf16x8*)&buf[lnm * 256 + uu];
          bf16x8 w1 = *(const bf16x8*)&buf[(16 + lnm) * 256 + uu];
#pragma unroll
          for (int t = 0; t < 2; t++) {
            acc[t][0] = __builtin_amdgcn_mfma_f32_16x16x32_bf16(w0, efrag[t][ks], acc[t][0], 0, 0, 0);
            acc[t][1] = __builtin_amdgcn_mfma_f32_16x16x32_bf16(w1, efrag[t][ks], acc[t][1], 0, 0, 0);
          }
        }
      }
      // ======== kh = 1 (Wst[1]) ========
      __syncthreads();                      // drains Wst[1]'s loads; Wst[0] free
      if (q + 2 < 128) stageW16(chunk_base(W1g, q + 2), Wst[0], tid);
      {
        const u16* buf = Wst[1];
#pragma unroll
        for (int ks = 0; ks < 8; ks++) {
          const int uu = ((ks * 4 + lnq) ^ (lnm & 7)) * 8;
          bf16x8 w0 = *(const bf16x8*)&buf[lnm * 256 + uu];
          bf16x8 w1 = *(const bf16x8*)&buf[(16 + lnm) * 256 + uu];
#pragma unroll
          for (int t = 0; t < 2; t++) {
            acc[t][0] = __builtin_amdgcn_mfma_f32_16x16x32_bf16(w0, efrag[t][8 + ks], acc[t][0], 0, 0, 0);
            acc[t][1] = __builtin_amdgcn_mfma_f32_16x16x32_bf16(w1, efrag[t][8 + ks], acc[t][1], 0, 0, 0);
          }
        }
      }
      // ---- epilogue: h1 = relu(acc + b1) -> wave-private h1c rows (packed b64) ----
#pragma unroll
      for (int ct = 0; ct < 2; ct++) {
        float4 bq = *(const float4*)&b1g[s * H + wc * 32 + ct * 16 + lnq * 4];
#pragma unroll
        for (int t = 0; t < 2; t++) {
          union { u16 u[4]; uint2 v; } pk;
          pk.u[0] = f2bf(fmaxf(acc[t][ct][0] + bq.x, 0.f));
          pk.u[1] = f2bf(fmaxf(acc[t][ct][1] + bq.y, 0.f));
          pk.u[2] = f2bf(fmaxf(acc[t][ct][2] + bq.z, 0.f));
          pk.u[3] = f2bf(fmaxf(acc[t][ct][3] + bq.w, 0.f));
          *(uint2*)&h1c[(wave * 32 + t * 16 + lnm) * H1STR + ct * 16 + lnq * 4] = pk.v;
        }
      }
      // ---- GEMM2 partial over this 32-wcol window (wave-private, no barrier) ----
      {
        bf16x8 bw = *(const bf16x8*)&W2T[((size_t)s * 16 + lnm) * H + wc * 32 + lnq * 8];
#pragma unroll
        for (int t = 0; t < 2; t++) {
          bf16x8 a2 = *(const bf16x8*)&h1c[(wave * 32 + t * 16 + lnm) * H1STR + lnq * 8];
          oacc[t] = __builtin_amdgcn_mfma_f32_16x16x32_bf16(a2, bw, oacc[t], 0, 0, 0);
        }
      }
    }
    // ---- end of source: sigmoid + alpha-weighted accumulate ----
    {
      float b2v = (lnm < NT) ? b2g[s * NT + lnm] : 0.f;
#pragma unroll
      for (int t = 0; t < 2; t++) {
#pragma unroll
        for (int g = 0; g < 4; g++) {
          float sig = 1.f / (1.f + __expf(-(oacc[t][g] + b2v)));
          fin[t][g] += alphS[j][wave * 32 + t * 16 + lnq * 4 + g] * sig;
        }
      }
    }
  }
  // combine partials across the 2 source-groups
  if (lnm < NT) {
#pragma unroll
    for (int t = 0; t < 2; t++) {
#pragma unroll
      for (int g = 0; g < 4; g++) {
        int rg = row0 + wave * 32 + t * 16 + lnq * 4 + g;
        atomicAdd(&out[(size_t)rg * NT + lnm], fin[t][g]);
      }
    }
  }
}

extern "C" void kernel_launch(void* const* d_in, const int* in_sizes, int n_in,
                              void* d_out, int out_size, void* d_ws, size_t ws_size,
                              hipStream_t stream) {
  const float* enc = (const float*)d_in[0];
  const float* mu  = (const float*)d_in[1];
  const float* Us  = (const float*)d_in[2];
  const float* W1  = (const float*)d_in[3];
  const float* b1  = (const float*)d_in[4];
  const float* W2  = (const float*)d_in[5];
  const float* b2  = (const float*)d_in[6];
  float* out = (float*)d_out;
  char* ws = (char*)d_ws;
  u16* W1T    = (u16*)(ws + WS_W1T);
  u16* UcatT  = (u16*)(ws + WS_UCT);
  u16* W2T    = (u16*)(ws + WS_W2T);
  float* cvec = (float*)(ws + WS_CVEC);
  float* alphT = (float*)(ws + WS_ALPH);

  dim3 tb(32, 8, 1);
  transpose_cast<<<dim3(16, 16, 8), tb, 0, stream>>>(W1, W1T, 512, 512, 512);
  transpose_cast<<<dim3(16, 2, 8),  tb, 0, stream>>>(Us, UcatT, 512, 64, 64);
  transpose_cast<<<dim3(16, 1, 8),  tb, 0, stream>>>(W2, W2T, 512, 12, 16);
  compute_c<<<512, 64, 0, stream>>>(mu, Us, cvec);
  routing<<<512, 256, 0, stream>>>(enc, UcatT, cvec, alphT);
  hipMemsetAsync(out, 0, (size_t)out_size * sizeof(float), stream);
  moe_main<<<512, 256, 0, stream>>>(enc, W1T, W2T, alphT, b1, b2, out);
}